// Round 2
// 576.917 us; speedup vs baseline: 1.0583x; 1.0583x over previous
//
#include <hip/hip_runtime.h>
#include <math.h>

#define S_FRAMES 64
#define C_CH 384
#define HW 3136          // 56*56
#define HW4 784          // HW/4
#define S_TOP 16
#define CNUM 48          // 384/8
#define NPLANES (S_FRAMES * C_CH)   // 24576

typedef float nt4 __attribute__((ext_vector_type(4)));   // native vec for nontemporal builtin

// ---------------- Kernel A: global average pool per (s,c) plane ----------------
// One wave (64 lanes) per plane, 4 planes per 256-thread block; shuffle-only
// reduction (no LDS, no __syncthreads). Planes are processed in DESCENDING
// frame order so that the low-s frames are the most recently read -> resident
// in the 256 MiB Infinity Cache when conv starts streaming at s=0.
__global__ __launch_bounds__(256) void pool_kernel(const float* __restrict__ x,
                                                   float* __restrict__ xg) {
    int wid  = blockIdx.x * 4 + (threadIdx.x >> 6);   // global wave id, [0, 24576)
    int lane = threadIdx.x & 63;
    int s = S_FRAMES - 1 - (wid / C_CH);              // reverse frame order
    int c = wid % C_CH;
    int plane = s * C_CH + c;                         // matches x layout

    const float4* p = (const float4*)(x + (size_t)plane * HW);
    float sum = 0.0f;
    #pragma unroll
    for (int k = 0; k < 12; k++) {                    // 12*64 = 768 float4
        float4 v = p[lane + k * 64];
        sum += (v.x + v.y) + (v.z + v.w);
    }
    if (lane < 16) {                                  // remaining 16 float4
        float4 v = p[768 + lane];
        sum += (v.x + v.y) + (v.z + v.w);
    }
    for (int off = 32; off > 0; off >>= 1)
        sum += __shfl_down(sum, off, 64);
    if (lane == 0) xg[plane] = sum * (1.0f / (float)HW);
}

// ---------------- Kernel B: scores -> top16 -> MLP -> softmax -> convk ----------------
// single block, 256 threads.
__global__ __launch_bounds__(256) void mlp_kernel(const float* __restrict__ xg,
                           const float* __restrict__ w_lin,
                           const float* __restrict__ w1,
                           const float* __restrict__ bn_g, const float* __restrict__ bn_b,
                           const float* __restrict__ bn_m, const float* __restrict__ bn_v,
                           const float* __restrict__ w2,
                           float* __restrict__ convk) {
    __shared__ float sc[S_FRAMES];
    __shared__ int   sel[S_TOP];
    __shared__ float w1s[2 * S_TOP * S_TOP];   // 512
    __shared__ float w2s[3 * 2 * S_TOP];       // 96
    __shared__ float bnS[2 * S_TOP], bnH[2 * S_TOP];
    int tid = threadIdx.x;

    // stage small weights (completed before the first __syncthreads below)
    w1s[tid]       = w1[tid];
    w1s[tid + 256] = w1[tid + 256];
    if (tid < 96) w2s[tid] = w2[tid];
    if (tid < 2 * S_TOP) {
        float scale = bn_g[tid] * rsqrtf(bn_v[tid] + 1e-5f);
        bnS[tid] = scale;
        bnH[tid] = bn_b[tid] - bn_m[tid] * scale;   // (h-m)*scale+b = h*scale + (b-m*scale)
    }

    // scores: 4 threads per frame, vectorized. thread (s,q) sums 96 elements.
    {
        int s = tid >> 2, q = tid & 3;
        const float4* xr = (const float4*)(xg + (size_t)s * C_CH) + q * 24;
        const float4* wl = (const float4*)(w_lin) + q * 24;
        float sum = 0.0f;
        #pragma unroll
        for (int k = 0; k < 24; k++) {
            float4 v = xr[k], w = wl[k];
            sum += v.x * w.x + v.y * w.y + v.z * w.z + v.w * w.w;
        }
        sum += __shfl_down(sum, 2, 4);
        sum += __shfl_down(sum, 1, 4);
        if (q == 0) sc[s] = sum;
    }
    __syncthreads();

    // stable top-16 (descending score, tie -> lower index), kept in temporal order.
    // threads 0..63 are exactly wave 0 -> 64-bit ballot is the selection mask.
    if (tid < S_FRAMES) {
        float my = sc[tid];
        int rank = 0;
        for (int s2 = 0; s2 < S_FRAMES; s2++) {
            float o = sc[s2];
            rank += (o > my) || (o == my && s2 < tid);
        }
        bool selected = (rank < S_TOP);
        unsigned long long mask = __ballot(selected);
        if (selected) {
            int pos = __popcll(mask & ((1ull << tid) - 1ull)); // ascending-index position
            sel[pos] = tid;
        }
    }
    __syncthreads();

    // per-channel MLP: (16) -> (32) -> BN -> ReLU -> (3) -> softmax
    for (int c = tid; c < C_CH; c += 256) {
        float sls[S_TOP];
        #pragma unroll
        for (int j = 0; j < S_TOP; j++) sls[j] = xg[(size_t)sel[j] * C_CH + c]; // coalesced per j
        float lg0 = 0.f, lg1 = 0.f, lg2 = 0.f;
        for (int o = 0; o < 2 * S_TOP; o++) {
            float h = 0.0f;
            #pragma unroll
            for (int j = 0; j < S_TOP; j++) h = fmaf(sls[j], w1s[o * S_TOP + j], h);
            h = fmaf(h, bnS[o], bnH[o]);
            h = fmaxf(h, 0.0f);
            lg0 = fmaf(h, w2s[o], lg0);
            lg1 = fmaf(h, w2s[2 * S_TOP + o], lg1);
            lg2 = fmaf(h, w2s[4 * S_TOP + o], lg2);
        }
        float mx = fmaxf(lg0, fmaxf(lg1, lg2));
        float e0 = expf(lg0 - mx), e1 = expf(lg1 - mx), e2 = expf(lg2 - mx);
        float inv = 1.0f / (e0 + e1 + e2);
        convk[c * 3 + 0] = e0 * inv;
        convk[c * 3 + 1] = e1 * inv;
        convk[c * 3 + 2] = e2 * inv;
    }
}

// ---------------- Kernel C: temporal shift + 3-tap depthwise temporal conv ----------------
// One thread per (c, hw float4 column); streams s with a sliding 3-tap window so x
// is read exactly once. Shift folded into tap index:
//   c <  48 : value(u) = x[u+1], valid u in [0,62]
//   c <  96 : value(u) = x[u-1], valid u in [1,63]
//   else    : value(u) = x[u],   valid u in [0,63]
// out[s] = k0*V(s-1) + k1*V(s) + k2*V(s+1)
// Stores are non-temporal: out is never re-read, keep x resident in L3.
__global__ __launch_bounds__(256) void conv_kernel(const float* __restrict__ x,
                            const float* __restrict__ convk,
                            float* __restrict__ out) {
    int idx = blockIdx.x * blockDim.x + threadIdx.x;
    if (idx >= C_CH * HW4) return;
    int c   = idx / HW4;
    int col = idx - c * HW4;

    float k0 = convk[c * 3 + 0];
    float k1 = convk[c * 3 + 1];
    float k2 = convk[c * 3 + 2];

    int delta, lo, hi;
    if (c < CNUM)          { delta =  1; lo = 0; hi = 62; }
    else if (c < 2 * CNUM) { delta = -1; lo = 1; hi = 63; }
    else                   { delta =  0; lo = 0; hi = 63; }

    const size_t S = (size_t)C_CH * HW4;       // float4 stride per frame
    const float4* xp = (const float4*)x + (size_t)c * HW4 + col;
    nt4*          op = (nt4*)out + (size_t)c * HW4 + col;

    const float4 zero = make_float4(0.f, 0.f, 0.f, 0.f);
    float4 vm = zero;
    float4 vc = (0 >= lo) ? xp[(size_t)delta * S] : zero;   // V(0); hi>=0 always

    #pragma unroll 4
    for (int s = 0; s < S_FRAMES; s++) {
        int u = s + 1;
        float4 vp = (u >= lo && u <= hi) ? xp[(size_t)(u + delta) * S] : zero;
        nt4 o;
        o.x = k0 * vm.x + k1 * vc.x + k2 * vp.x;
        o.y = k0 * vm.y + k1 * vc.y + k2 * vp.y;
        o.z = k0 * vm.z + k1 * vc.z + k2 * vp.z;
        o.w = k0 * vm.w + k1 * vc.w + k2 * vp.w;
        __builtin_nontemporal_store(o, &op[(size_t)s * S]);
        vm = vc; vc = vp;
    }
}

extern "C" void kernel_launch(void* const* d_in, const int* in_sizes, int n_in,
                              void* d_out, int out_size, void* d_ws, size_t ws_size,
                              hipStream_t stream) {
    const float* x       = (const float*)d_in[0];
    const float* w_lin   = (const float*)d_in[1];
    const float* w1      = (const float*)d_in[2];
    const float* bn_g    = (const float*)d_in[3];
    const float* bn_b    = (const float*)d_in[4];
    const float* bn_m    = (const float*)d_in[5];
    const float* bn_v    = (const float*)d_in[6];
    const float* w2      = (const float*)d_in[7];
    float* out = (float*)d_out;

    float* xg    = (float*)d_ws;               // 64*384 floats
    float* convk = xg + S_FRAMES * C_CH;       // 384*3 floats

    pool_kernel<<<NPLANES / 4, 256, 0, stream>>>(x, xg);
    mlp_kernel<<<1, 256, 0, stream>>>(xg, w_lin, w1, bn_g, bn_b, bn_m, bn_v, w2, convk);
    conv_kernel<<<(C_CH * HW4 + 255) / 256, 256, 0, stream>>>(x, convk, out);
}